// Round 7
// baseline (185.869 us; speedup 1.0000x reference)
//
#include <hip/hip_runtime.h>
#include <cstddef>

#define EPS 1e-5f
static constexpr int Bn = 64, Cn = 64, Hn = 56, Wn = 56, HWn = Hn * Wn; // 3136

typedef __attribute__((ext_vector_type(8))) short short8;
typedef __attribute__((ext_vector_type(8))) unsigned short ushort8;
typedef __attribute__((ext_vector_type(4))) float floatx4;
typedef __attribute__((ext_vector_type(16))) float floatx16;
typedef __attribute__((ext_vector_type(4))) unsigned int uintx4;
typedef __attribute__((ext_vector_type(2))) unsigned int uintx2;

__device__ __forceinline__ unsigned pack_rne(float a, float b) {
    unsigned ua = __float_as_uint(a), ub = __float_as_uint(b);
    ua = ua + 0x7fffu + ((ua >> 16) & 1u);
    ub = ub + 0x7fffu + ((ub >> 16) & 1u);
    return __builtin_amdgcn_perm(ub, ua, 0x07060302);
}
__device__ __forceinline__ unsigned pack_trunc(float a, float b) {
    return __builtin_amdgcn_perm(__float_as_uint(b), __float_as_uint(a), 0x07060302);
}
__device__ __forceinline__ ushort8 pmax(ushort8 a, ushort8 b) {
    return __builtin_elementwise_max(a, b);   // valid bf16 max for values >= 0
}
__device__ __forceinline__ float bf_lo(unsigned u) { return __uint_as_float(u << 16); }
__device__ __forceinline__ float bf_hi(unsigned u) { return __uint_as_float(u & 0xffff0000u); }

// node0 layout (bf16): [b][chunk=8][px=3136][j=8]

// ---------------------------------------------------------------------------
// K1: node0 = relu(bn1(conv1x1(x,w1))). bn scale folded into A-frags.
// Software-pipelined x gather: loads for tile tt+1 issue before MFMAs of tt.
// Chunk-split uint2 stores (dense 256-B runs per half-wave).
// ---------------------------------------------------------------------------
__global__ __launch_bounds__(256) void k1_conv1(
    const float* __restrict__ x, const float* __restrict__ w1,
    const float* __restrict__ bg, const float* __restrict__ bb,
    const float* __restrict__ bm, const float* __restrict__ bv,
    unsigned short* __restrict__ node0)
{
    __shared__ float scs[64], shs[64];
    const int tid = threadIdx.x;
    if (tid < 64) {
        float sc = bg[tid] * rsqrtf(bv[tid] + EPS);
        scs[tid] = sc;
        shs[tid] = bb[tid] - bm[tid] * sc;
    }
    __syncthreads();
    const int lane = tid & 63;
    const int wv   = tid >> 6;
    const int m    = lane & 15;
    const int quad = lane >> 4;
    const int qoff = quad * 8;

    short8 afr[4][2];
    float shv[16];
    #pragma unroll
    for (int t = 0; t < 4; ++t) {
        const float sc = scs[t * 16 + m];
        #pragma unroll
        for (int kk = 0; kk < 2; ++kk) {
            const float* wp = w1 + (t * 16 + m) * 64 + kk * 32 + qoff;
            floatx4 f0 = *(const floatx4*)wp;
            floatx4 f1 = *(const floatx4*)(wp + 4);
            uintx4 u;
            u.x = pack_rne(f0[0] * sc, f0[1] * sc);
            u.y = pack_rne(f0[2] * sc, f0[3] * sc);
            u.z = pack_rne(f1[0] * sc, f1[1] * sc);
            u.w = pack_rne(f1[2] * sc, f1[3] * sc);
            afr[t][kk] = *(short8*)&u;
        }
        #pragma unroll
        for (int i = 0; i < 4; ++i) shv[t * 4 + i] = shs[t * 16 + quad * 4 + i];
    }

    float xv[2][16];
    // prologue: load tile 0
    {
        const int P = blockIdx.x * 256;
        const int b = P / HWn, p0 = P - b * HWn;
        const float* xb = x + (size_t)b * 64 * HWn + p0 + wv * 16 + m;
        #pragma unroll
        for (int j = 0; j < 8; ++j) {
            xv[0][j]     = xb[(size_t)(qoff + j) * HWn];
            xv[0][8 + j] = xb[(size_t)(32 + qoff + j) * HWn];
        }
    }

    #pragma unroll
    for (int tt = 0; tt < 4; ++tt) {
        const int cur = tt & 1, nxt = cur ^ 1;
        if (tt < 3) {   // issue next tile's loads before this tile's MFMAs
            const int P = blockIdx.x * 256 + (tt + 1) * 64;
            const int b = P / HWn, p0 = P - b * HWn;
            const float* xb = x + (size_t)b * 64 * HWn + p0 + wv * 16 + m;
            #pragma unroll
            for (int j = 0; j < 8; ++j) {
                xv[nxt][j]     = xb[(size_t)(qoff + j) * HWn];
                xv[nxt][8 + j] = xb[(size_t)(32 + qoff + j) * HWn];
            }
        }

        floatx4 acc[4];
        #pragma unroll
        for (int t = 0; t < 4; ++t) acc[t] = (floatx4){0.f, 0.f, 0.f, 0.f};

        #pragma unroll
        for (int kk = 0; kk < 2; ++kk) {
            uintx4 u;
            u.x = pack_trunc(xv[cur][kk * 8 + 0], xv[cur][kk * 8 + 1]);
            u.y = pack_trunc(xv[cur][kk * 8 + 2], xv[cur][kk * 8 + 3]);
            u.z = pack_trunc(xv[cur][kk * 8 + 4], xv[cur][kk * 8 + 5]);
            u.w = pack_trunc(xv[cur][kk * 8 + 6], xv[cur][kk * 8 + 7]);
            short8 bfr = *(short8*)&u;
            #pragma unroll
            for (int t = 0; t < 4; ++t)
                acc[t] = __builtin_amdgcn_mfma_f32_16x16x32_bf16(afr[t][kk], bfr, acc[t], 0, 0, 0);
        }

        const int P = blockIdx.x * 256 + tt * 64;
        const int b = P / HWn, p0 = P - b * HWn;
        const int chunkbase = (quad >> 1);
        const int j0 = (quad & 1) * 4;
        #pragma unroll
        for (int t = 0; t < 4; ++t) {
            float v0 = acc[t][0] + shv[t * 4 + 0]; v0 = v0 > 0.f ? v0 : 0.f;
            float v1 = acc[t][1] + shv[t * 4 + 1]; v1 = v1 > 0.f ? v1 : 0.f;
            float v2 = acc[t][2] + shv[t * 4 + 2]; v2 = v2 > 0.f ? v2 : 0.f;
            float v3 = acc[t][3] + shv[t * 4 + 3]; v3 = v3 > 0.f ? v3 : 0.f;
            uintx2 st;
            st.x = pack_rne(v0, v1);
            st.y = pack_rne(v2, v3);
            int chunk = t * 2 + chunkbase;
            *(uintx2*)(node0 + ((size_t)(b * 8 + chunk) * HWn + p0 + wv * 16 + m) * 8 + j0) = st;
        }
    }
}

// ---------------------------------------------------------------------------
// K23 fused v2: persistent 8-row strip per block. Phase A: packed-u16 pools,
// rolling rings persist across sub-bands (halo 1.5x), cat tile in swizzled
// LDS (16-B units, u^(px&15) -> no pad, bank-uniform). Phase B per 4-row
// sub-band: 7 waves x 32-px 32x32 MFMA; out staged fp32 in LDS, then stored
// cooperatively as per-o 896-B contiguous runs (write amp 2.0 -> 1.14).
// ---------------------------------------------------------------------------
__global__ __launch_bounds__(512, 4) void k23_fused(
    const unsigned short* __restrict__ node0, const float* __restrict__ w2,
    const float* __restrict__ bg, const float* __restrict__ bb,
    const float* __restrict__ bm, const float* __restrict__ bv,
    float* __restrict__ out)
{
    __shared__ unsigned short ct[224 * 128];    // 57344 B: cat tile / fp32 out tile
    __shared__ unsigned short wl[1024 * 8];     // 16 KB frag-linear w2
    __shared__ float scs[64], shs[64];
    const int tid = threadIdx.x;
    if (tid < 64) {
        float sc = bg[tid] * rsqrtf(bv[tid] + EPS);
        scs[tid] = sc;
        shs[tid] = bb[tid] - bm[tid] * sc;
    }
    // stage w2 -> wl: ci = (t*8+kt)*64 + lane', 16 B each
    #pragma unroll
    for (int q = 0; q < 2; ++q) {
        int ci = tid * 2 + q;
        int lane_ = ci & 63, tk = ci >> 6;
        int t = tk >> 3, kt = tk & 7, n_ = lane_ & 31, h_ = lane_ >> 5;
        const float* wp = w2 + (t * 32 + n_) * 128 + kt * 16 + h_ * 8;
        floatx4 f0 = *(const floatx4*)wp;
        floatx4 f1 = *(const floatx4*)(wp + 4);
        uintx4 u;
        u.x = pack_rne(f0[0], f0[1]);
        u.y = pack_rne(f0[2], f0[3]);
        u.z = pack_rne(f1[0], f1[1]);
        u.w = pack_rne(f1[2], f1[3]);
        *(uintx4*)(wl + (size_t)ci * 8) = u;
    }
    __syncthreads();

    const int lane = tid & 63;
    const int wv = tid >> 6;            // phase A: channel chunk 0..7
    const int b = blockIdx.x / 7;
    const int lo = (blockIdx.x % 7) * 8;
    const int col = lane;
    const bool act = col < Wn;
    const unsigned short* base = node0 + ((size_t)(b * 8 + wv) * HWn) * 8;

    // ring state (persists across phase-B interludes)
    const ushort8 zz = (ushort8)0;
    float hs1[8], hs2[8];
    ushort8 h5a = zz, h5b = zz, h5c = zz, h5d = zz, nh1 = zz, nh2 = zz;
    uintx4 apq; apq.x = 0u; apq.y = 0u; apq.z = 0u; apq.w = 0u;
    #pragma unroll
    for (int j = 0; j < 8; ++j) hs1[j] = hs2[j] = 0.f;

    #pragma unroll 1
    for (int q = 0; q < 2; ++q) {
        const int rstart = lo - 2 + (q ? 8 : 0);
        const int niter = q ? 4 : 8;
        // ---- phase A iterations ----
        #pragma unroll
        for (int i = 0; i < 8; ++i) {
            if (i >= niter) break;
            const int r = rstart + i;
            ushort8 d[5];
            #pragma unroll
            for (int dd = 0; dd < 5; ++dd) {
                int cc = col + dd - 2;
                bool ok = act && ((unsigned)cc < (unsigned)Wn) && ((unsigned)r < (unsigned)Hn);
                d[dd] = ok ? *(const ushort8*)(base + (size_t)(r * Wn + cc) * 8) : zz;
            }
            ushort8 hm5 = pmax(pmax(pmax(d[0], d[1]), pmax(d[2], d[3])), d[4]);
            ushort8 m5 = pmax(pmax(pmax(h5a, h5b), pmax(h5c, h5d)), hm5);
            h5a = h5b; h5b = h5c; h5c = h5d; h5d = hm5;

            const uintx4 ul = *(const uintx4*)&d[1];
            const uintx4 uv = *(const uintx4*)&d[2];
            const uintx4 ur = *(const uintx4*)&d[3];
            float a2[8];
            const bool vr = (unsigned)(r - 1) < (unsigned)Hn;
            #pragma unroll
            for (int w = 0; w < 4; ++w) {
                float hsum0 = bf_lo(ul[w]) + bf_lo(uv[w]) + bf_lo(ur[w]);
                float hsum1 = bf_hi(ul[w]) + bf_hi(uv[w]) + bf_hi(ur[w]);
                a2[w * 2 + 0] = vr ? (hs2[w * 2 + 0] + hs1[w * 2 + 0] + hsum0) * (1.f / 9.f) : 0.f;
                a2[w * 2 + 1] = vr ? (hs2[w * 2 + 1] + hs1[w * 2 + 1] + hsum1) * (1.f / 9.f) : 0.f;
                hs2[w * 2 + 0] = hs1[w * 2 + 0]; hs1[w * 2 + 0] = hsum0;
                hs2[w * 2 + 1] = hs1[w * 2 + 1]; hs1[w * 2 + 1] = hsum1;
            }
            uintx4 ap;
            ap.x = pack_rne(a2[0], a2[1]);
            ap.y = pack_rne(a2[2], a2[3]);
            ap.z = pack_rne(a2[4], a2[5]);
            ap.w = pack_rne(a2[6], a2[7]);
            uintx4 al, ar;
            #pragma unroll
            for (int w = 0; w < 4; ++w) {
                unsigned u = ap[w];
                unsigned lu = __shfl_up(u, 1);
                unsigned ru = __shfl_down(u, 1);
                al[w] = (lane == 0) ? 0u : lu;
                ar[w] = (lane == 63) ? 0u : ru;
            }
            ushort8 nh = pmax(pmax(*(ushort8*)&al, *(ushort8*)&ap), *(ushort8*)&ar);
            ushort8 m3 = pmax(pmax(nh2, nh1), nh);
            nh2 = nh1; nh1 = nh;

            const int ro = r - 2;   // both avg (apq) and maxsum (m5+m3) rows complete
            if (act && ro >= lo && ro < lo + 8) {
                const int pxt = ((ro - lo) & 3) * Wn + col;
                const int sw = pxt & 15;
                *(uintx4*)(ct + (size_t)pxt * 128 + (size_t)(wv ^ sw) * 8) = apq;
                const uintx4 u5 = *(const uintx4*)&m5;
                const uintx4 u3 = *(const uintx4*)&m3;
                uintx4 st;
                #pragma unroll
                for (int w = 0; w < 4; ++w)
                    st[w] = pack_rne(bf_lo(u5[w]) + bf_lo(u3[w]), bf_hi(u5[w]) + bf_hi(u3[w]));
                *(uintx4*)(ct + (size_t)pxt * 128 + (size_t)((8 + wv) ^ sw) * 8) = st;
            }
            apq = ap;
        }
        __syncthreads();

        // ---- phase B: conv2 on sub-band q (4 rows = 224 px) ----
        floatx16 acc0, acc1;
        const int n = lane & 31;
        const int h = lane >> 5;
        if (wv < 7) {
            short8 afr[2][8];
            #pragma unroll
            for (int t = 0; t < 2; ++t)
                #pragma unroll
                for (int kt = 0; kt < 8; ++kt)
                    afr[t][kt] = *(const short8*)(wl + ((size_t)((t * 8 + kt) * 64 + lane)) * 8);
            const int px = wv * 32 + n;
            #pragma unroll
            for (int i = 0; i < 16; ++i) { acc0[i] = 0.f; acc1[i] = 0.f; }
            #pragma unroll
            for (int kt = 0; kt < 8; ++kt) {
                const int u = (kt * 2 + h) ^ (px & 15);
                short8 bfr = *(const short8*)(ct + (size_t)px * 128 + (size_t)u * 8);
                acc0 = __builtin_amdgcn_mfma_f32_32x32x16_bf16(afr[0][kt], bfr, acc0, 0, 0, 0);
                acc1 = __builtin_amdgcn_mfma_f32_32x32x16_bf16(afr[1][kt], bfr, acc1, 0, 0, 0);
            }
        }
        __syncthreads();
        // stage fp32 out tile [64 o][224 px] into ct
        if (wv < 7) {
            float* ot = (float*)ct;
            const int px = wv * 32 + n;
            #pragma unroll
            for (int r = 0; r < 16; ++r) {
                int o = (r & 3) + 8 * (r >> 2) + 4 * h;
                float v0 = fmaf(acc0[r], scs[o], shs[o]);
                ot[o * 224 + px] = v0 > 0.f ? v0 : 0.f;
                float v1 = fmaf(acc1[r], scs[o + 32], shs[o + 32]);
                ot[(o + 32) * 224 + px] = v1 > 0.f ? v1 : 0.f;
            }
        }
        __syncthreads();
        // cooperative store: per-o 896-B contiguous runs
        {
            const float* ot = (const float*)ct;
            const size_t obase = (size_t)b * 64 * HWn + (size_t)(lo + 4 * q) * Wn;
            #pragma unroll
            for (int it = 0; it < 7; ++it) {
                int ci = it * 512 + tid;            // 3584 x 16-B chunks
                int o = ci / 56;
                int c4 = (ci - o * 56) * 4;
                floatx4 v = *(const floatx4*)(ot + ci * 4);   // o*224 + c4 == ci*4
                *(floatx4*)(out + obase + (size_t)o * HWn + c4) = v;
            }
        }
        __syncthreads();
    }
}

extern "C" void kernel_launch(void* const* d_in, const int* in_sizes, int n_in,
                              void* d_out, int out_size, void* d_ws, size_t ws_size,
                              hipStream_t stream)
{
    const float* x   = (const float*)d_in[0];
    const float* w1  = (const float*)d_in[1];
    const float* w2  = (const float*)d_in[2];
    const float* b1g = (const float*)d_in[3];
    const float* b1b = (const float*)d_in[4];
    const float* b1m = (const float*)d_in[5];
    const float* b1v = (const float*)d_in[6];
    const float* b2g = (const float*)d_in[7];
    const float* b2b = (const float*)d_in[8];
    const float* b2m = (const float*)d_in[9];
    const float* b2v = (const float*)d_in[10];

    float* out = (float*)d_out;
    unsigned short* node0 = (unsigned short*)d_ws;   // 25.7 MB

    k1_conv1<<<dim3(784), dim3(256), 0, stream>>>(x, w1, b1g, b1b, b1m, b1v, node0);
    k23_fused<<<dim3(Bn * 7), dim3(512), 0, stream>>>(node0, w2, b2g, b2b, b2m, b2v, out);
}

// Round 8
// 159.925 us; speedup vs baseline: 1.1622x; 1.1622x over previous
//
#include <hip/hip_runtime.h>
#include <cstddef>

#define EPS 1e-5f
static constexpr int Bn = 64, Cn = 64, Hn = 56, Wn = 56, HWn = Hn * Wn; // 3136
static constexpr int XS = 65; // k1 LDS transpose stride (floats): 2-way max on write & read

typedef __attribute__((ext_vector_type(8))) short short8;
typedef __attribute__((ext_vector_type(8))) unsigned short ushort8;
typedef __attribute__((ext_vector_type(4))) float floatx4;
typedef __attribute__((ext_vector_type(16))) float floatx16;
typedef __attribute__((ext_vector_type(4))) unsigned int uintx4;
typedef __attribute__((ext_vector_type(2))) unsigned int uintx2;

__device__ __forceinline__ unsigned pack_rne(float a, float b) {
    unsigned ua = __float_as_uint(a), ub = __float_as_uint(b);
    ua = ua + 0x7fffu + ((ua >> 16) & 1u);
    ub = ub + 0x7fffu + ((ub >> 16) & 1u);
    return __builtin_amdgcn_perm(ub, ua, 0x07060302);
}
__device__ __forceinline__ unsigned pack_trunc(float a, float b) {
    return __builtin_amdgcn_perm(__float_as_uint(b), __float_as_uint(a), 0x07060302);
}
__device__ __forceinline__ ushort8 pmax(ushort8 a, ushort8 b) {
    return __builtin_elementwise_max(a, b);   // valid bf16 max for values >= 0
}
__device__ __forceinline__ float bf_lo(unsigned u) { return __uint_as_float(u << 16); }
__device__ __forceinline__ float bf_hi(unsigned u) { return __uint_as_float(u & 0xffff0000u); }

// Layouts (bf16):
//   node0: [b][chunk=8][px=3136][j=8]
//   cat:   [b][chunk=16][px=3136][j=8]   ch 0-7 avg, 8-15 maxsum

// ---------------------------------------------------------------------------
// K1: node0 = relu(bn1(conv1x1(x,w1))). bn scale folded into A-frags.
// x staged through LDS via float4 loads (1-KB contiguous runs per wave),
// double-buffered: tile t+1 global loads in flight during tile t MFMAs.
// Chunk-split uint2 stores (dense 256-B runs per half-wave).
// ---------------------------------------------------------------------------
__global__ __launch_bounds__(256) void k1_conv1(
    const float* __restrict__ x, const float* __restrict__ w1,
    const float* __restrict__ bg, const float* __restrict__ bb,
    const float* __restrict__ bm, const float* __restrict__ bv,
    unsigned short* __restrict__ node0)
{
    __shared__ float xs[2][64 * XS];   // 2 x 16.6 KB px-major fp32 tiles
    __shared__ float scs[64], shs[64];
    const int tid = threadIdx.x;
    if (tid < 64) {
        float sc = bg[tid] * rsqrtf(bv[tid] + EPS);
        scs[tid] = sc;
        shs[tid] = bb[tid] - bm[tid] * sc;
    }
    __syncthreads();
    const int lane = tid & 63;
    const int wv   = tid >> 6;
    const int m    = lane & 15;
    const int quad = lane >> 4;
    const int qoff = quad * 8;

    short8 afr[4][2];
    float shv[16];
    #pragma unroll
    for (int t = 0; t < 4; ++t) {
        const float sc = scs[t * 16 + m];
        #pragma unroll
        for (int kk = 0; kk < 2; ++kk) {
            const float* wp = w1 + (t * 16 + m) * 64 + kk * 32 + qoff;
            floatx4 f0 = *(const floatx4*)wp;
            floatx4 f1 = *(const floatx4*)(wp + 4);
            uintx4 u;
            u.x = pack_rne(f0[0] * sc, f0[1] * sc);
            u.y = pack_rne(f0[2] * sc, f0[3] * sc);
            u.z = pack_rne(f1[0] * sc, f1[1] * sc);
            u.w = pack_rne(f1[2] * sc, f1[3] * sc);
            afr[t][kk] = *(short8*)&u;
        }
        #pragma unroll
        for (int i = 0; i < 4; ++i) shv[t * 4 + i] = shs[t * 16 + quad * 4 + i];
    }

    // staging helpers: tile = 64 px x 64 ch fp32; thread covers 4 float4s
    floatx4 stg[4];
    auto ldtile = [&](int tt) {
        const int P = blockIdx.x * 256 + tt * 64;
        const int b = P / HWn, p0 = P - b * HWn;   // 64 | 3136: no image crossing
        #pragma unroll
        for (int q = 0; q < 4; ++q) {
            int idx = q * 256 + tid;               // (c = idx/16, f = idx%16)
            int c = idx >> 4, f = idx & 15;
            stg[q] = *(const floatx4*)(x + (size_t)(b * 64 + c) * HWn + p0 + f * 4);
        }
    };
    auto sttile = [&](int buf) {
        #pragma unroll
        for (int q = 0; q < 4; ++q) {
            int idx = q * 256 + tid;
            int c = idx >> 4, f = idx & 15;
            #pragma unroll
            for (int k = 0; k < 4; ++k)
                xs[buf][(f * 4 + k) * XS + c] = stg[q][k];   // 2-way banks (XS=65)
        }
    };

    ldtile(0);
    sttile(0);

    #pragma unroll
    for (int tt = 0; tt < 4; ++tt) {
        __syncthreads();                 // xs[tt&1] ready for all threads
        if (tt < 3) ldtile(tt + 1);      // global loads overlap compute

        const int P = blockIdx.x * 256 + tt * 64;
        const int b = P / HWn, p0 = P - b * HWn;
        const float* xr = &xs[tt & 1][(wv * 16 + m) * XS];

        floatx4 acc[4];
        #pragma unroll
        for (int t = 0; t < 4; ++t) acc[t] = (floatx4){0.f, 0.f, 0.f, 0.f};

        #pragma unroll
        for (int kk = 0; kk < 2; ++kk) {
            float f[8];
            #pragma unroll
            for (int j = 0; j < 8; ++j) f[j] = xr[kk * 32 + qoff + j];  // 2-way banks
            uintx4 u;
            u.x = pack_trunc(f[0], f[1]);
            u.y = pack_trunc(f[2], f[3]);
            u.z = pack_trunc(f[4], f[5]);
            u.w = pack_trunc(f[6], f[7]);
            short8 bfr = *(short8*)&u;
            #pragma unroll
            for (int t = 0; t < 4; ++t)
                acc[t] = __builtin_amdgcn_mfma_f32_16x16x32_bf16(afr[t][kk], bfr, acc[t], 0, 0, 0);
        }

        const int chunkbase = (quad >> 1);
        const int j0 = (quad & 1) * 4;
        #pragma unroll
        for (int t = 0; t < 4; ++t) {
            float v0 = acc[t][0] + shv[t * 4 + 0]; v0 = v0 > 0.f ? v0 : 0.f;
            float v1 = acc[t][1] + shv[t * 4 + 1]; v1 = v1 > 0.f ? v1 : 0.f;
            float v2 = acc[t][2] + shv[t * 4 + 2]; v2 = v2 > 0.f ? v2 : 0.f;
            float v3 = acc[t][3] + shv[t * 4 + 3]; v3 = v3 > 0.f ? v3 : 0.f;
            uintx2 st;
            st.x = pack_rne(v0, v1);
            st.y = pack_rne(v2, v3);
            int chunk = t * 2 + chunkbase;
            *(uintx2*)(node0 + ((size_t)(b * 8 + chunk) * HWn + p0 + wv * 16 + m) * 8 + j0) = st;
        }

        if (tt < 3) sttile((tt + 1) & 1);   // write next buffer; sync at loop top
    }
}

// ---------------------------------------------------------------------------
// K2: pools, packed-u16 max domain, 8-row bands, prefetched rows.
// Block = (b, 8-row band, chunk-half), 256 thr = 4 waves = 4 chunks.
// ---------------------------------------------------------------------------
__global__ __launch_bounds__(256) void k2_pools(
    const unsigned short* __restrict__ node0, unsigned short* __restrict__ cat)
{
    const int tid = threadIdx.x;
    const int lane = tid & 63;
    const int wv = tid >> 6;
    const int bid = blockIdx.x;
    const int half = bid & 1;
    const int band = (bid >> 1) % 7;
    const int b = bid / 14;
    const int chunk = half * 4 + wv;
    const int lo = band * 8;
    const int col = lane;
    const bool act = col < Wn;
    const unsigned short* base = node0 + ((size_t)(b * 8 + chunk) * HWn) * 8;
    unsigned short* cavg = cat + ((size_t)(b * 16 + chunk) * HWn) * 8;
    unsigned short* cmax = cat + ((size_t)(b * 16 + 8 + chunk) * HWn) * 8;

    const ushort8 zz = (ushort8)0;
    auto load5 = [&](int r, ushort8* d) {
        #pragma unroll
        for (int dd = 0; dd < 5; ++dd) {
            int cc = col + dd - 2;
            bool ok = act && ((unsigned)cc < (unsigned)Wn) && ((unsigned)r < (unsigned)Hn);
            d[dd] = ok ? *(const ushort8*)(base + (size_t)(r * Wn + cc) * 8) : zz;
        }
    };

    float hs1[8], hs2[8];
    ushort8 h5a = zz, h5b = zz, h5c = zz, h5d = zz, nh1 = zz, nh2 = zz;
    #pragma unroll
    for (int j = 0; j < 8; ++j) hs1[j] = hs2[j] = 0.f;

    ushort8 d[5];
    load5(lo - 2, d);

    #pragma unroll
    for (int i = 0; i < 12; ++i) {
        const int r = lo - 2 + i;
        ushort8 dn[5];
        if (i < 11) load5(r + 1, dn);    // prefetch next row during compute

        ushort8 hm5 = pmax(pmax(pmax(d[0], d[1]), pmax(d[2], d[3])), d[4]);
        ushort8 m5 = pmax(pmax(pmax(h5a, h5b), pmax(h5c, h5d)), hm5);
        h5a = h5b; h5b = h5c; h5c = h5d; h5d = hm5;

        const uintx4 ul = *(const uintx4*)&d[1];
        const uintx4 uv = *(const uintx4*)&d[2];
        const uintx4 ur = *(const uintx4*)&d[3];
        float a2[8];
        const int r2 = r - 1, r3 = r - 2;
        const bool v2 = (unsigned)r2 < (unsigned)Hn;
        #pragma unroll
        for (int w = 0; w < 4; ++w) {
            float hsum0 = bf_lo(ul[w]) + bf_lo(uv[w]) + bf_lo(ur[w]);
            float hsum1 = bf_hi(ul[w]) + bf_hi(uv[w]) + bf_hi(ur[w]);
            a2[w * 2 + 0] = v2 ? (hs2[w * 2 + 0] + hs1[w * 2 + 0] + hsum0) * (1.f / 9.f) : 0.f;
            a2[w * 2 + 1] = v2 ? (hs2[w * 2 + 1] + hs1[w * 2 + 1] + hsum1) * (1.f / 9.f) : 0.f;
            hs2[w * 2 + 0] = hs1[w * 2 + 0]; hs1[w * 2 + 0] = hsum0;
            hs2[w * 2 + 1] = hs1[w * 2 + 1]; hs1[w * 2 + 1] = hsum1;
        }
        uintx4 ap;
        ap.x = pack_rne(a2[0], a2[1]);
        ap.y = pack_rne(a2[2], a2[3]);
        ap.z = pack_rne(a2[4], a2[5]);
        ap.w = pack_rne(a2[6], a2[7]);
        uintx4 al, ar;
        #pragma unroll
        for (int w = 0; w < 4; ++w) {
            unsigned u = ap[w];
            unsigned lu = __shfl_up(u, 1);
            unsigned ru = __shfl_down(u, 1);
            al[w] = (lane == 0) ? 0u : lu;
            ar[w] = (lane == 63) ? 0u : ru;
        }
        ushort8 nh = pmax(pmax(*(ushort8*)&al, *(ushort8*)&ap), *(ushort8*)&ar);
        ushort8 m3 = pmax(pmax(nh2, nh1), nh);
        nh2 = nh1; nh1 = nh;

        if (act && r2 >= lo && r2 < lo + 8)
            *(uintx4*)(cavg + (size_t)(r2 * Wn + col) * 8) = ap;
        if (act && r3 >= lo && r3 < lo + 8) {
            const uintx4 u5 = *(const uintx4*)&m5;
            const uintx4 u3 = *(const uintx4*)&m3;
            uintx4 st;
            #pragma unroll
            for (int w = 0; w < 4; ++w)
                st[w] = pack_rne(bf_lo(u5[w]) + bf_lo(u3[w]), bf_hi(u5[w]) + bf_hi(u3[w]));
            *(uintx4*)(cmax + (size_t)(r3 * Wn + col) * 8) = st;
        }
        #pragma unroll
        for (int dd = 0; dd < 5; ++dd) d[dd] = dn[dd];
    }
}

// ---------------------------------------------------------------------------
// K3: out = relu(bn2(conv1x1(cat,w2))), 32x32x16 MFMA, w2 staged once per
// block into LDS. Both px-tiles unrolled -> 16 outstanding B-frag loads.
// ---------------------------------------------------------------------------
__global__ __launch_bounds__(256) void k3_conv2(
    const unsigned short* __restrict__ cat, const float* __restrict__ w2,
    const float* __restrict__ bg, const float* __restrict__ bb,
    const float* __restrict__ bm, const float* __restrict__ bv,
    float* __restrict__ out)
{
    __shared__ unsigned short wl[1024 * 8];  // 16 KB frag-linear w2 (bf16)
    __shared__ float scs[64], shs[64];
    const int tid = threadIdx.x;
    if (tid < 64) {
        float sc = bg[tid] * rsqrtf(bv[tid] + EPS);
        scs[tid] = sc;
        shs[tid] = bb[tid] - bm[tid] * sc;
    }
    #pragma unroll
    for (int q = 0; q < 4; ++q) {
        int ci = tid * 4 + q;
        int lane_ = ci & 63, tk = ci >> 6;
        int t = tk >> 3, kt = tk & 7, n_ = lane_ & 31, h_ = lane_ >> 5;
        const float* wp = w2 + (t * 32 + n_) * 128 + kt * 16 + h_ * 8;
        floatx4 f0 = *(const floatx4*)wp;
        floatx4 f1 = *(const floatx4*)(wp + 4);
        uintx4 u;
        u.x = pack_rne(f0[0], f0[1]);
        u.y = pack_rne(f0[2], f0[3]);
        u.z = pack_rne(f1[0], f1[1]);
        u.w = pack_rne(f1[2], f1[3]);
        *(uintx4*)(wl + (size_t)ci * 8) = u;
    }
    __syncthreads();

    const int lane = tid & 63;
    const int wv = tid >> 6;
    const int n = lane & 31;
    const int h = lane >> 5;

    short8 afr[2][8];
    #pragma unroll
    for (int t = 0; t < 2; ++t)
        #pragma unroll
        for (int kt = 0; kt < 8; ++kt)
            afr[t][kt] = *(const short8*)(wl + ((size_t)((t * 8 + kt) * 64 + lane)) * 8);

    #pragma unroll
    for (int s = 0; s < 2; ++s) {
        const int tile = (blockIdx.x * 4 + wv) * 2 + s;   // 32-px tiles, 3136%32==0
        const int b = tile / 98;
        const int p0 = (tile - b * 98) * 32;

        floatx16 acc0, acc1;
        #pragma unroll
        for (int i = 0; i < 16; ++i) { acc0[i] = 0.f; acc1[i] = 0.f; }

        #pragma unroll
        for (int kt = 0; kt < 8; ++kt) {
            short8 bfr = *(const short8*)(cat + ((size_t)(b * 16 + kt * 2 + h) * HWn + p0 + n) * 8);
            acc0 = __builtin_amdgcn_mfma_f32_32x32x16_bf16(afr[0][kt], bfr, acc0, 0, 0, 0);
            acc1 = __builtin_amdgcn_mfma_f32_32x32x16_bf16(afr[1][kt], bfr, acc1, 0, 0, 0);
        }

        float* ob = out + (size_t)b * 64 * HWn + p0 + n;
        #pragma unroll
        for (int r = 0; r < 16; ++r) {
            int o = (r & 3) + 8 * (r >> 2) + 4 * h;
            float v0 = fmaf(acc0[r], scs[o], shs[o]);
            ob[(size_t)o * HWn] = v0 > 0.f ? v0 : 0.f;
            float v1 = fmaf(acc1[r], scs[o + 32], shs[o + 32]);
            ob[(size_t)(o + 32) * HWn] = v1 > 0.f ? v1 : 0.f;
        }
    }
}

extern "C" void kernel_launch(void* const* d_in, const int* in_sizes, int n_in,
                              void* d_out, int out_size, void* d_ws, size_t ws_size,
                              hipStream_t stream)
{
    const float* x   = (const float*)d_in[0];
    const float* w1  = (const float*)d_in[1];
    const float* w2  = (const float*)d_in[2];
    const float* b1g = (const float*)d_in[3];
    const float* b1b = (const float*)d_in[4];
    const float* b1m = (const float*)d_in[5];
    const float* b1v = (const float*)d_in[6];
    const float* b2g = (const float*)d_in[7];
    const float* b2b = (const float*)d_in[8];
    const float* b2m = (const float*)d_in[9];
    const float* b2v = (const float*)d_in[10];

    float* out = (float*)d_out;
    unsigned short* node0 = (unsigned short*)d_ws;            // 25.7 MB
    unsigned short* cat   = node0 + (size_t)Bn * HWn * 64;    // 51.4 MB

    k1_conv1<<<dim3(784), dim3(256), 0, stream>>>(x, w1, b1g, b1b, b1m, b1v, node0);
    k2_pools<<<dim3(Bn * 14), dim3(256), 0, stream>>>(node0, cat);
    k3_conv2<<<dim3(784), dim3(256), 0, stream>>>(cat, w2, b2g, b2b, b2m, b2v, out);
}